// Round 13
// baseline (124.886 us; speedup 1.0000x reference)
//
#include <hip/hip_runtime.h>
#include <math.h>

#define BATCH 2
#define SEQ   4096
#define DIN   256
#define NH    8
#define DH    32            // head dim (dk = dv = 32)
#define BH    (BATCH*NH)    // 16
#define NSPLIT 4            // key-split (R4: 8 = pure merge/write tax)
#define KRANGE (SEQ/NSPLIT) // 1024 keys per block
#define TILES  (KRANGE/64)  // 16 tiles of 64 keys (R5: 128-key intervals hurt)
#define QTILE  512          // R11-proven: 512 q/block, 8 waves x 64 q/wave
// Ledger (R0-R12): QTILE=128 regression (R1); NSPLIT=8 tax (R3/R4); 128-key
// staging regression (R5); explicit qt-rotation regression (R6); permlane
// P-transpose VALU-bound, slower than pbuf (R4/R7); fused split-K merge w/
// device fences -> L2 writeback disaster (R9, 204us); QTILE=512 8-wave keep
// (R11); merge-uint4 -6us (R10); proj 2-phase 32KiB -5us (R12).
// Total-level noise +/-3-4us; per-kernel dur_us / cross-round deltas are the signal.

typedef short bf16x8 __attribute__((ext_vector_type(8)));
typedef float f32x4  __attribute__((ext_vector_type(4)));

// raw v_exp_f32 (base-2). Scores bounded -> no denorm fixup needed.
#if defined(__has_builtin)
#if __has_builtin(__builtin_amdgcn_exp2f)
#define EXP2(x) __builtin_amdgcn_exp2f(x)
#else
#define EXP2_ASM 1
#endif
#else
#define EXP2_ASM 1
#endif
#ifdef EXP2_ASM
__device__ __forceinline__ float exp2_raw(float x) {
    float r;
    asm("v_exp_f32 %0, %1\n\ts_nop 1" : "=v"(r) : "v"(x));
    return r;
}
#define EXP2(x) exp2_raw(x)
#endif

#define SC2 0.25508218f     // log2(e)/sqrt(32) — folded into Q at projection

__device__ __forceinline__ unsigned short f2bf(float f) {
    unsigned int u = __builtin_bit_cast(unsigned int, f);
    u += 0x7fffu + ((u >> 16) & 1u);
    return (unsigned short)(u >> 16);
}

// pack 2 rounded bf16 (round-half-up), one v_perm + 2 adds
__device__ __forceinline__ unsigned int pack_bf2(float f0, float f1) {
    unsigned int u0 = __builtin_bit_cast(unsigned int, f0) + 0x8000u;
    unsigned int u1 = __builtin_bit_cast(unsigned int, f1) + 0x8000u;
    return __builtin_amdgcn_perm(u1, u0, 0x07060302u);
}

// pack 2 TRUNCATED bf16, single v_perm (hot attn loop). Truncation bias
// cancels exactly in softmax: l is computed from the same truncated P.
__device__ __forceinline__ unsigned int pack_bf2_t(float f0, float f1) {
    return __builtin_amdgcn_perm(__builtin_bit_cast(unsigned int, f1),
                                 __builtin_bit_cast(unsigned int, f0),
                                 0x07060302u);
}

#if defined(__has_builtin)
#if __has_builtin(__builtin_amdgcn_global_load_lds)
#define HAS_ASYNC_LDS 1
#endif
#endif

// async global->LDS, 16B/lane: wave-uniform LDS base, HW scatters lane i to
// base + i*16 (verified R5-R10).
__device__ __forceinline__ void stage16(const unsigned short* g,
                                        unsigned short* lds_base, int lane) {
#ifdef HAS_ASYNC_LDS
    __builtin_amdgcn_global_load_lds(
        (const __attribute__((address_space(1))) unsigned int*)g,
        (__attribute__((address_space(3))) unsigned int*)lds_base, 16, 0, 0);
#else
    *(bf16x8*)(lds_base + (size_t)lane * 8) = *(const bf16x8*)g;
#endif
}

// ---------------- prep: W -> Wt bf16 (48 blocks) + x -> xb bf16 (1024) ------
// x conversion hoisted here ONCE (R8: proj previously re-read x as fp32 12x
// and re-converted 12x; hoisting was worth ~2.6us).
__global__ __launch_bounds__(256) void prep_kernel(
    const float* __restrict__ x,
    const float* __restrict__ Wq, const float* __restrict__ Wk, const float* __restrict__ Wv,
    unsigned short* __restrict__ Wt, unsigned short* __restrict__ xb)
{
    __shared__ float ws[64][65];
    if (blockIdx.x >= 48) {
        // x: 2*4096*256 = 2,097,152 floats; 8 per thread; 1024 blocks
        int gid = (blockIdx.x - 48) * 256 + threadIdx.x;
        const float4* xs = (const float4*)x;
        float4 a = xs[(size_t)gid * 2];
        float4 b = xs[(size_t)gid * 2 + 1];
        uint4 p = { pack_bf2(a.x, a.y), pack_bf2(a.z, a.w),
                    pack_bf2(b.x, b.y), pack_bf2(b.z, b.w) };
        ((uint4*)xb)[gid] = p;
        return;
    }
    const int t = threadIdx.x;
    int wsel = blockIdx.x >> 4;
    int tile = blockIdx.x & 15;
    int tr = (tile >> 2) * 64;
    int tc = (tile & 3) * 64;
    const float* __restrict__ W = (wsel == 0) ? Wq : (wsel == 1) ? Wk : Wv;
    #pragma unroll
    for (int i = 0; i < 16; i++) {
        int row = i * 4 + (t >> 6), col = t & 63;
        ws[row][col] = W[(size_t)(tr + row) * DIN + tc + col];
    }
    __syncthreads();
    unsigned short* dst = Wt + (size_t)wsel * DIN * DIN;
    #pragma unroll
    for (int i = 0; i < 16; i++) {
        int orow = i * 4 + (t >> 6), ocol = t & 63;
        dst[(size_t)(tc + orow) * DIN + tr + ocol] = f2bf(ws[ocol][orow]);
    }
}

// ---------------- proj v4: 4-phase double-buffered pipeline, 32 KiB ---------
// R13: v3's phases were stall-then-compute (stage 8 -> bar -> MFMA). v4
// applies the attn kernel's proven 2-buffer pattern at 2-kb-chunk granularity:
// prologue stages pair 0; each phase syncs, issues pair ph+1 into buf^1, then
// computes pair ph from buf. Staging latency hides under MFMA within-block
// AND cross-block (5 blocks/CU at 32 KiB). kb order preserved -> bit-identical.
__global__ __launch_bounds__(256) void proj_kernel(
    const unsigned short* __restrict__ xb, const unsigned short* __restrict__ Wt,
    unsigned short* __restrict__ qh, unsigned short* __restrict__ kh,
    unsigned short* __restrict__ vt)
{
    __shared__ __align__(16) unsigned short abuf[2][2][4][64][8];  // 16 KiB
    __shared__ __align__(16) unsigned short bbuf[2][2][4][64][8];  // 16 KiB

    const int wsel = blockIdx.y;
    const int w    = threadIdx.x >> 6;
    const int lane = threadIdx.x & 63;
    const int quad = lane >> 4;
    const int l16  = lane & 15;

    const int sl   = lane ^ (lane >> 3);      // producer: lane -> slot
    const int sl16 = sl >> 2, squad = sl & 3;
    const int s_ = (l16 << 2) | quad;         // consumer slot for (l16, quad)
    const int jj = (s_ & 56) | ((s_ ^ (s_ >> 3)) & 7);

    int arow0, brow0;
    const unsigned short* Wbase;
    const unsigned short* Xbase;
    unsigned short (*wdst)[2][4][64][8];
    unsigned short (*xdst)[2][4][64][8];
    if (wsel < 2) {
        int tt = blockIdx.x >> 7, nt = blockIdx.x & 127;
        arow0 = tt * 64; brow0 = nt * 64;
        Wbase = Wt + (size_t)wsel * DIN * DIN + (size_t)arow0 * DIN;
        Xbase = xb + (size_t)brow0 * DIN;
        wdst = abuf; xdst = bbuf;
    } else {
        int nt = blockIdx.x >> 2, tt = blockIdx.x & 3;
        arow0 = nt * 64; brow0 = tt * 64;
        Xbase = xb + (size_t)arow0 * DIN;
        Wbase = Wt + (size_t)2 * DIN * DIN + (size_t)brow0 * DIN;
        wdst = bbuf; xdst = abuf;
    }

    // wave w stages 4 tiles per phase: id = w*4+i in 0..15 ->
    // op = id>>3 (0:W, 1:X), kbl = (id>>2)&1, rt = id&3
    // stage pair `pp` (kb = pp*2 + kbl) into dbuf slot `db`.
    #define PROJ_STAGE(pp, db)                                                 \
        { _Pragma("unroll")                                                    \
          for (int i_ = 0; i_ < 4; i_++) {                                     \
              int id_ = w * 4 + i_;                                            \
              int kbl_ = (id_ >> 2) & 1, rt_ = id_ & 3;                        \
              int kbg_ = (pp) * 2 + kbl_;                                      \
              if (id_ < 8)                                                     \
                  stage16(Wbase + (size_t)(rt_ * 16 + sl16) * DIN + kbg_ * 32  \
                          + squad * 8, &wdst[db][kbl_][rt_][0][0], lane);      \
              else                                                             \
                  stage16(Xbase + (size_t)(rt_ * 16 + sl16) * DIN + kbg_ * 32  \
                          + squad * 8, &xdst[db][kbl_][rt_][0][0], lane);      \
          } }

    f32x4 acc[4];
    #pragma unroll
    for (int c = 0; c < 4; c++) acc[c] = (f32x4){0.f, 0.f, 0.f, 0.f};

    PROJ_STAGE(0, 0);

    #pragma unroll
    for (int ph = 0; ph < 4; ph++) {
        const int buf = ph & 1;
        __syncthreads();               // pair ph staged into buf; buf^1 free
        if (ph + 1 < 4) PROJ_STAGE(ph + 1, buf ^ 1);

        #pragma unroll
        for (int kbl = 0; kbl < 2; kbl++) {
            bf16x8 af = *(const bf16x8*)&abuf[buf][kbl][w][jj][0];
            #pragma unroll
            for (int c = 0; c < 4; c++) {
                bf16x8 bfr = *(const bf16x8*)&bbuf[buf][kbl][c][jj][0];
                acc[c] = __builtin_amdgcn_mfma_f32_16x16x32_bf16(af, bfr, acc[c], 0, 0, 0);
            }
        }
    }
    #undef PROJ_STAGE

    if (wsel < 2) {
        const float scl = (wsel == 0) ? SC2 : 1.0f;
        unsigned short* __restrict__ dst0 = (wsel == 0) ? qh : kh;
        const int t0 = arow0 + w * 16;
        const int h = t0 >> 5, d0 = (t0 & 31) + quad * 4;
        #pragma unroll
        for (int c = 0; c < 4; c++) {
            int n = brow0 + c * 16 + l16;
            int b = n >> 12, n12 = n & 4095;
            unsigned int u01 = pack_bf2(acc[c][0] * scl, acc[c][1] * scl);
            unsigned int u23 = pack_bf2(acc[c][2] * scl, acc[c][3] * scl);
            *(uint2*)&dst0[((size_t)(b * NH + h) * SEQ + n12) * DH + d0] = make_uint2(u01, u23);
        }
    } else {
        const int n0w = arow0 + w * 16;
        const int b = n0w >> 12, nbase = (n0w & 4095) + quad * 4;
        #pragma unroll
        for (int c = 0; c < 4; c++) {
            int t = brow0 + c * 16;
            int h = t >> 5, d = (t & 31) + l16;
            unsigned int u01 = pack_bf2(acc[c][0], acc[c][1]);
            unsigned int u23 = pack_bf2(acc[c][2], acc[c][3]);
            *(uint2*)&vt[((size_t)(b * NH + h) * DH + d) * SEQ + nbase] = make_uint2(u01, u23);
        }
    }
}

// ---------------- Flash attention v19 (R11-proven): 8-wave, 512 q/block -----
// Per-wave inner loop = R2's proven kernel verbatim (64 q/wave, pbuf
// round-trip, per-qt setprio). 8 waves share each 64-key K/V tile: waves 0-3
// stage K quarters, waves 4-7 stage V quarters (1 stage16/wave/tile).
__global__ __launch_bounds__(512, 4) void attn_kernel(
    const unsigned short* __restrict__ qh,
    const unsigned short* __restrict__ kh,
    const unsigned short* __restrict__ vt,
    unsigned short* __restrict__ po, float* __restrict__ pl)
{
    __shared__ __align__(16) unsigned short pbuf[8][2][16][64];  // 32 KiB
    __shared__ __align__(16) unsigned short kbuf[2][4][64][8];   // 8 KiB
    __shared__ __align__(16) unsigned short vbuf[2][4][64][8];   // 8 KiB

    const int tid  = threadIdx.x;
    const int wave = tid >> 6;        // 0..7
    const int lane = tid & 63;
    const int quad = lane >> 4;
    const int l16  = lane & 15;
    const int sw   = l16 & 7;         // pbuf XOR swizzle key

    const int bh = blockIdx.x & 15;   // head -> XCD pinning
    const int qb = (blockIdx.x >> 4) & 7;
    const int ks = blockIdx.x >> 7;   // key-split 0..3
    const int q0 = qb * QTILE + wave * 64;
    const int kbase = ks * KRANGE;

    const unsigned short* __restrict__ Qp = qh + (size_t)bh * SEQ * DH;
    const unsigned short* __restrict__ Kp = kh + (size_t)bh * SEQ * DH;
    const unsigned short* __restrict__ Vp = vt + (size_t)bh * DH * SEQ;

    const int sl    = lane ^ (lane >> 3);
    const int sl16  = sl >> 2, squad = sl & 3;

    // staging role: waves 0-3 stage K quarter kw; waves 4-7 stage V quarter kw
    const int kw = wave & 3;
    const unsigned short* src;
    size_t sstride;
    if (wave < 4) {
        src = Kp + (size_t)(kbase + kw * 16 + sl16) * DH + squad * 8;
        sstride = (size_t)64 * DH;
    } else {
        const int vdh = kw >> 1, vkh = kw & 1;
        src = Vp + (size_t)(vdh * 16 + sl16) * SEQ + kbase + vkh * 32 + squad * 8;
        sstride = 64;
    }
    unsigned short* dstA = (wave < 4) ? &kbuf[0][kw][0][0] : &vbuf[0][kw][0][0];
    unsigned short* dstB = (wave < 4) ? &kbuf[1][kw][0][0] : &vbuf[1][kw][0][0];

    const int s_ = (l16 << 2) | quad;
    const int jj = (s_ & 56) | ((s_ ^ (s_ >> 3)) & 7);

    bf16x8 qf[4];
    #pragma unroll
    for (int i = 0; i < 4; i++)
        qf[i] = *(const bf16x8*)(Qp + (size_t)(q0 + i * 16 + l16) * DH + quad * 8);

    const bf16x8 ones = {0x3F80, 0x3F80, 0x3F80, 0x3F80,
                         0x3F80, 0x3F80, 0x3F80, 0x3F80};

    f32x4 o[4][2];
    f32x4 lones[4];
    #pragma unroll
    for (int i = 0; i < 4; i++) {
        o[i][0] = (f32x4){0.f, 0.f, 0.f, 0.f};
        o[i][1] = (f32x4){0.f, 0.f, 0.f, 0.f};
        lones[i] = (f32x4){0.f, 0.f, 0.f, 0.f};
    }
    const f32x4 z = {0.f, 0.f, 0.f, 0.f};

    // prologue: stage tile 0 into buffer 0 (1 stage16 per wave)
    stage16(src, dstA, lane);
    src += sstride;

    for (int t = 0; t < TILES; t++) {
        const int buf = t & 1;

        __syncthreads();   // tile t staged; buf^1 free

        if (t + 1 < TILES) {
            stage16(src, buf ? dstA : dstB, lane);   // stage into buf^1
            src += sstride;
        }

        // read shared K/V fragments ONCE per wave, reuse across 4 q-subtiles
        bf16x8 kf[4], vf[4];
        #pragma unroll
        for (int c = 0; c < 4; c++) kf[c] = *(const bf16x8*)&kbuf[buf][c][jj][0];
        #pragma unroll
        for (int f = 0; f < 4; f++) vf[f] = *(const bf16x8*)&vbuf[buf][f][jj][0];

        #pragma unroll
        for (int qt = 0; qt < 4; qt++) {
            const int pr = qt & 1;    // pbuf parity region
            #pragma unroll
            for (int c = 0; c < 4; c++) {
                f32x4 s = __builtin_amdgcn_mfma_f32_16x16x32_bf16(kf[c], qf[qt], z, 0, 0, 0);
                float e0 = EXP2(s[0]);
                float e1 = EXP2(s[1]);
                float e2 = EXP2(s[2]);
                float e3 = EXP2(s[3]);
                int chs = ((c * 2 + (quad >> 1)) ^ sw) * 8 + (quad & 1) * 4;
                *(uint2*)&pbuf[wave][pr][l16][chs] =
                    make_uint2(pack_bf2_t(e0, e1), pack_bf2_t(e2, e3));
            }
            bf16x8 pf0 = *(const bf16x8*)&pbuf[wave][pr][l16][((0 + quad) ^ sw) * 8];
            bf16x8 pf1 = *(const bf16x8*)&pbuf[wave][pr][l16][((4 + quad) ^ sw) * 8];
            __builtin_amdgcn_s_setprio(1);   // T5: keep matrix pipe fed in PV
            o[qt][0] = __builtin_amdgcn_mfma_f32_16x16x32_bf16(pf0, vf[0], o[qt][0], 0, 0, 0);
            o[qt][0] = __builtin_amdgcn_mfma_f32_16x16x32_bf16(pf1, vf[1], o[qt][0], 0, 0, 0);
            o[qt][1] = __builtin_amdgcn_mfma_f32_16x16x32_bf16(pf0, vf[2], o[qt][1], 0, 0, 0);
            o[qt][1] = __builtin_amdgcn_mfma_f32_16x16x32_bf16(pf1, vf[3], o[qt][1], 0, 0, 0);
            lones[qt] = __builtin_amdgcn_mfma_f32_16x16x32_bf16(pf0, ones, lones[qt], 0, 0, 0);
            lones[qt] = __builtin_amdgcn_mfma_f32_16x16x32_bf16(pf1, ones, lones[qt], 0, 0, 0);
            __builtin_amdgcn_s_setprio(0);
        }
    }

    // epilogue: bf16 partial O + fp32 partial l (lones rows align with o rows)
    const size_t obase = (size_t)(ks * BH + bh) * SEQ;
    #pragma unroll
    for (int qt = 0; qt < 4; qt++) {
        if (l16 == 0) {
            #pragma unroll
            for (int r = 0; r < 4; r++)
                pl[obase + q0 + qt * 16 + quad * 4 + r] = lones[qt][r];
        }
        #pragma unroll
        for (int r = 0; r < 4; r++) {
            int n = q0 + qt * 16 + quad * 4 + r;
            unsigned short* dst = po + (obase + n) * DH;
            dst[l16]      = f2bf(o[qt][0][r]);
            dst[16 + l16] = f2bf(o[qt][1][r]);
        }
    }
}

// ---------------- merge v2 (R10-proven): uint4 po reads, 32B/thread out -----
__global__ __launch_bounds__(256) void merge_kernel(
    const unsigned short* __restrict__ po, const float* __restrict__ pl,
    float* __restrict__ out)
{
    int t    = blockIdx.x * 256 + threadIdx.x;   // 0 .. 256K-1
    int d16  = t & 3;                            // 16B chunk within 32-dh row
    int pair = t >> 2;
    int bh   = pair >> 12;
    int n    = pair & 4095;
    float s0 = 0.f, s1 = 0.f, s2 = 0.f, s3 = 0.f;
    float s4 = 0.f, s5 = 0.f, s6 = 0.f, s7 = 0.f, ls = 0.f;
    #pragma unroll
    for (int sp = 0; sp < NSPLIT; sp++) {
        size_t base = (size_t)(sp * BH + bh) * SEQ + n;
        uint4 v = ((const uint4*)(po + base * DH))[d16];
        s0 += __builtin_bit_cast(float, v.x << 16);
        s1 += __builtin_bit_cast(float, v.x & 0xFFFF0000u);
        s2 += __builtin_bit_cast(float, v.y << 16);
        s3 += __builtin_bit_cast(float, v.y & 0xFFFF0000u);
        s4 += __builtin_bit_cast(float, v.z << 16);
        s5 += __builtin_bit_cast(float, v.z & 0xFFFF0000u);
        s6 += __builtin_bit_cast(float, v.w << 16);
        s7 += __builtin_bit_cast(float, v.w & 0xFFFF0000u);
        ls += pl[base];
    }
    float inv = 1.f / ls;
    int b = bh >> 3, h = bh & 7;
    float4 o0 = {s0 * inv, s1 * inv, s2 * inv, s3 * inv};
    float4 o1 = {s4 * inv, s5 * inv, s6 * inv, s7 * inv};
    float4* dst = (float4*)(out + ((size_t)b * SEQ + n) * (NH * DH) + h * DH);
    dst[d16 * 2]     = o0;
    dst[d16 * 2 + 1] = o1;
}

extern "C" void kernel_launch(void* const* d_in, const int* in_sizes, int n_in,
                              void* d_out, int out_size, void* d_ws, size_t ws_size,
                              hipStream_t stream)
{
    const float* x  = (const float*)d_in[0];
    const float* Wq = (const float*)d_in[1];
    const float* Wk = (const float*)d_in[2];
    const float* Wv = (const float*)d_in[3];
    float* out = (float*)d_out;

    // ws: qh|kh|vt (4 MiB each) | Wt (384 KiB) | po (16 MiB) | pl (1 MiB) | xb (4 MiB)
    unsigned short* qh = (unsigned short*)d_ws;
    unsigned short* kh = qh + (size_t)BH * SEQ * DH;
    unsigned short* vt = kh + (size_t)BH * SEQ * DH;
    unsigned short* Wt = vt + (size_t)BH * SEQ * DH;
    unsigned short* po = Wt + 3 * DIN * DIN;
    float* pl = (float*)(po + (size_t)NSPLIT * BH * SEQ * DH);
    unsigned short* xb = (unsigned short*)(pl + (size_t)NSPLIT * BH * SEQ);

    prep_kernel<<<dim3(48 + 1024), 256, 0, stream>>>(x, Wq, Wk, Wv, Wt, xb);
    proj_kernel<<<dim3(512, 3), 256, 0, stream>>>(xb, Wt, qh, kh, vt);
    attn_kernel<<<dim3(BH * (SEQ / QTILE) * NSPLIT), 512, 0, stream>>>(qh, kh, vt, po, pl);
    merge_kernel<<<dim3(1024), 256, 0, stream>>>(po, pl, out);
}

// Round 14
// 123.160 us; speedup vs baseline: 1.0140x; 1.0140x over previous
//
#include <hip/hip_runtime.h>
#include <math.h>

#define BATCH 2
#define SEQ   4096
#define DIN   256
#define NH    8
#define DH    32            // head dim (dk = dv = 32)
#define BH    (BATCH*NH)    // 16
#define NSPLIT 4            // key-split (R4: 8 = pure merge/write tax)
#define KRANGE (SEQ/NSPLIT) // 1024 keys per block
#define TILES  (KRANGE/64)  // 16 tiles of 64 keys (R5: 128-key intervals hurt)
#define QTILE  512          // R11-proven: 512 q/block, 8 waves x 64 q/wave
// Ledger (R0-R13): QTILE=128 regression (R1); NSPLIT=8 tax (R3/R4); 128-key
// staging regression (R5); explicit qt-rotation regression (R6); permlane
// P-transpose VALU-bound, slower than pbuf (R4/R7); fused split-K merge w/
// device fences -> L2 writeback disaster (R9, 204us); QTILE=512 8-wave keep
// (R11); merge-uint4 -6us (R10); proj 2-phase 32KiB -5us (R12); proj
// intra-block dbuf pipeline neutral (R13) -> REVERTED to v3 here.
// This is the best-measured configuration: R12 = 123.8us total.

typedef short bf16x8 __attribute__((ext_vector_type(8)));
typedef float f32x4  __attribute__((ext_vector_type(4)));

// raw v_exp_f32 (base-2). Scores bounded -> no denorm fixup needed.
#if defined(__has_builtin)
#if __has_builtin(__builtin_amdgcn_exp2f)
#define EXP2(x) __builtin_amdgcn_exp2f(x)
#else
#define EXP2_ASM 1
#endif
#else
#define EXP2_ASM 1
#endif
#ifdef EXP2_ASM
__device__ __forceinline__ float exp2_raw(float x) {
    float r;
    asm("v_exp_f32 %0, %1\n\ts_nop 1" : "=v"(r) : "v"(x));
    return r;
}
#define EXP2(x) exp2_raw(x)
#endif

#define SC2 0.25508218f     // log2(e)/sqrt(32) — folded into Q at projection

__device__ __forceinline__ unsigned short f2bf(float f) {
    unsigned int u = __builtin_bit_cast(unsigned int, f);
    u += 0x7fffu + ((u >> 16) & 1u);
    return (unsigned short)(u >> 16);
}

// pack 2 rounded bf16 (round-half-up), one v_perm + 2 adds
__device__ __forceinline__ unsigned int pack_bf2(float f0, float f1) {
    unsigned int u0 = __builtin_bit_cast(unsigned int, f0) + 0x8000u;
    unsigned int u1 = __builtin_bit_cast(unsigned int, f1) + 0x8000u;
    return __builtin_amdgcn_perm(u1, u0, 0x07060302u);
}

// pack 2 TRUNCATED bf16, single v_perm (hot attn loop). Truncation bias
// cancels exactly in softmax: l is computed from the same truncated P.
__device__ __forceinline__ unsigned int pack_bf2_t(float f0, float f1) {
    return __builtin_amdgcn_perm(__builtin_bit_cast(unsigned int, f1),
                                 __builtin_bit_cast(unsigned int, f0),
                                 0x07060302u);
}

#if defined(__has_builtin)
#if __has_builtin(__builtin_amdgcn_global_load_lds)
#define HAS_ASYNC_LDS 1
#endif
#endif

// async global->LDS, 16B/lane: wave-uniform LDS base, HW scatters lane i to
// base + i*16 (verified R5-R10).
__device__ __forceinline__ void stage16(const unsigned short* g,
                                        unsigned short* lds_base, int lane) {
#ifdef HAS_ASYNC_LDS
    __builtin_amdgcn_global_load_lds(
        (const __attribute__((address_space(1))) unsigned int*)g,
        (__attribute__((address_space(3))) unsigned int*)lds_base, 16, 0, 0);
#else
    *(bf16x8*)(lds_base + (size_t)lane * 8) = *(const bf16x8*)g;
#endif
}

// ---------------- prep: W -> Wt bf16 (48 blocks) + x -> xb bf16 (1024) ------
// x conversion hoisted here ONCE (R8: proj previously re-read x as fp32 12x
// and re-converted 12x; hoisting was worth ~2.6us).
__global__ __launch_bounds__(256) void prep_kernel(
    const float* __restrict__ x,
    const float* __restrict__ Wq, const float* __restrict__ Wk, const float* __restrict__ Wv,
    unsigned short* __restrict__ Wt, unsigned short* __restrict__ xb)
{
    __shared__ float ws[64][65];
    if (blockIdx.x >= 48) {
        // x: 2*4096*256 = 2,097,152 floats; 8 per thread; 1024 blocks
        int gid = (blockIdx.x - 48) * 256 + threadIdx.x;
        const float4* xs = (const float4*)x;
        float4 a = xs[(size_t)gid * 2];
        float4 b = xs[(size_t)gid * 2 + 1];
        uint4 p = { pack_bf2(a.x, a.y), pack_bf2(a.z, a.w),
                    pack_bf2(b.x, b.y), pack_bf2(b.z, b.w) };
        ((uint4*)xb)[gid] = p;
        return;
    }
    const int t = threadIdx.x;
    int wsel = blockIdx.x >> 4;
    int tile = blockIdx.x & 15;
    int tr = (tile >> 2) * 64;
    int tc = (tile & 3) * 64;
    const float* __restrict__ W = (wsel == 0) ? Wq : (wsel == 1) ? Wk : Wv;
    #pragma unroll
    for (int i = 0; i < 16; i++) {
        int row = i * 4 + (t >> 6), col = t & 63;
        ws[row][col] = W[(size_t)(tr + row) * DIN + tc + col];
    }
    __syncthreads();
    unsigned short* dst = Wt + (size_t)wsel * DIN * DIN;
    #pragma unroll
    for (int i = 0; i < 16; i++) {
        int orow = i * 4 + (t >> 6), ocol = t & 63;
        dst[(size_t)(tc + orow) * DIN + tr + ocol] = f2bf(ws[ocol][orow]);
    }
}

// ---------------- proj v3 (R12-proven): 2-phase single-buffer, 32 KiB -------
// Split K-accumulation into two phases over kb (0-3, 4-7), single-buffered
// 16 KiB per operand: LDS 32 KiB -> 5 blocks/CU (was 2 at 64 KiB). Exposed
// phase-2 staging latency is covered cross-block. kb order preserved ->
// bit-identical acc. (R13: intra-block dbuf pipelining on top = neutral.)
__global__ __launch_bounds__(256) void proj_kernel(
    const unsigned short* __restrict__ xb, const unsigned short* __restrict__ Wt,
    unsigned short* __restrict__ qh, unsigned short* __restrict__ kh,
    unsigned short* __restrict__ vt)
{
    __shared__ __align__(16) unsigned short abuf[4][4][64][8];  // 16 KiB
    __shared__ __align__(16) unsigned short bbuf[4][4][64][8];  // 16 KiB

    const int wsel = blockIdx.y;
    const int w    = threadIdx.x >> 6;
    const int lane = threadIdx.x & 63;
    const int quad = lane >> 4;
    const int l16  = lane & 15;

    const int sl   = lane ^ (lane >> 3);      // producer: lane -> slot
    const int sl16 = sl >> 2, squad = sl & 3;
    const int s_ = (l16 << 2) | quad;         // consumer slot for (l16, quad)
    const int jj = (s_ & 56) | ((s_ ^ (s_ >> 3)) & 7);

    int arow0, brow0;
    const unsigned short* Wbase;
    const unsigned short* Xbase;
    unsigned short (*wdst)[4][64][8];
    unsigned short (*xdst)[4][64][8];
    if (wsel < 2) {
        int tt = blockIdx.x >> 7, nt = blockIdx.x & 127;
        arow0 = tt * 64; brow0 = nt * 64;
        Wbase = Wt + (size_t)wsel * DIN * DIN + (size_t)arow0 * DIN;
        Xbase = xb + (size_t)brow0 * DIN;
        wdst = abuf; xdst = bbuf;
    } else {
        int nt = blockIdx.x >> 2, tt = blockIdx.x & 3;
        arow0 = nt * 64; brow0 = tt * 64;
        Xbase = xb + (size_t)arow0 * DIN;
        Wbase = Wt + (size_t)2 * DIN * DIN + (size_t)brow0 * DIN;
        wdst = bbuf; xdst = abuf;
    }

    f32x4 acc[4];
    #pragma unroll
    for (int c = 0; c < 4; c++) acc[c] = (f32x4){0.f, 0.f, 0.f, 0.f};

    #pragma unroll
    for (int ph = 0; ph < 2; ph++) {
        if (ph) __syncthreads();   // phase-0 reads done before overwrite
        // stage 16 tiles per operand quarter: wave w stages kb_local=w, rt 0-3
        #pragma unroll
        for (int i = 0; i < 4; i++) {
            int id = w * 4 + i;
            int kbl = id >> 2, rt = id & 3;
            int kbg = ph * 4 + kbl;
            stage16(Wbase + (size_t)(rt * 16 + sl16) * DIN + kbg * 32 + squad * 8,
                    &wdst[kbl][rt][0][0], lane);
        }
        #pragma unroll
        for (int i = 0; i < 4; i++) {
            int id = w * 4 + i;
            int kbl = id >> 2, rt = id & 3;
            int kbg = ph * 4 + kbl;
            stage16(Xbase + (size_t)(rt * 16 + sl16) * DIN + kbg * 32 + squad * 8,
                    &xdst[kbl][rt][0][0], lane);
        }
        __syncthreads();

        #pragma unroll
        for (int kbl = 0; kbl < 4; kbl++) {
            bf16x8 af = *(const bf16x8*)&abuf[kbl][w][jj][0];
            #pragma unroll
            for (int c = 0; c < 4; c++) {
                bf16x8 bfr = *(const bf16x8*)&bbuf[kbl][c][jj][0];
                acc[c] = __builtin_amdgcn_mfma_f32_16x16x32_bf16(af, bfr, acc[c], 0, 0, 0);
            }
        }
    }

    if (wsel < 2) {
        const float scl = (wsel == 0) ? SC2 : 1.0f;
        unsigned short* __restrict__ dst0 = (wsel == 0) ? qh : kh;
        const int t0 = arow0 + w * 16;
        const int h = t0 >> 5, d0 = (t0 & 31) + quad * 4;
        #pragma unroll
        for (int c = 0; c < 4; c++) {
            int n = brow0 + c * 16 + l16;
            int b = n >> 12, n12 = n & 4095;
            unsigned int u01 = pack_bf2(acc[c][0] * scl, acc[c][1] * scl);
            unsigned int u23 = pack_bf2(acc[c][2] * scl, acc[c][3] * scl);
            *(uint2*)&dst0[((size_t)(b * NH + h) * SEQ + n12) * DH + d0] = make_uint2(u01, u23);
        }
    } else {
        const int n0w = arow0 + w * 16;
        const int b = n0w >> 12, nbase = (n0w & 4095) + quad * 4;
        #pragma unroll
        for (int c = 0; c < 4; c++) {
            int t = brow0 + c * 16;
            int h = t >> 5, d = (t & 31) + l16;
            unsigned int u01 = pack_bf2(acc[c][0], acc[c][1]);
            unsigned int u23 = pack_bf2(acc[c][2], acc[c][3]);
            *(uint2*)&vt[((size_t)(b * NH + h) * DH + d) * SEQ + nbase] = make_uint2(u01, u23);
        }
    }
}

// ---------------- Flash attention v19 (R11-proven): 8-wave, 512 q/block -----
// Per-wave inner loop = R2's proven kernel verbatim (64 q/wave, pbuf
// round-trip, per-qt setprio). 8 waves share each 64-key K/V tile: waves 0-3
// stage K quarters, waves 4-7 stage V quarters (1 stage16/wave/tile).
__global__ __launch_bounds__(512, 4) void attn_kernel(
    const unsigned short* __restrict__ qh,
    const unsigned short* __restrict__ kh,
    const unsigned short* __restrict__ vt,
    unsigned short* __restrict__ po, float* __restrict__ pl)
{
    __shared__ __align__(16) unsigned short pbuf[8][2][16][64];  // 32 KiB
    __shared__ __align__(16) unsigned short kbuf[2][4][64][8];   // 8 KiB
    __shared__ __align__(16) unsigned short vbuf[2][4][64][8];   // 8 KiB

    const int tid  = threadIdx.x;
    const int wave = tid >> 6;        // 0..7
    const int lane = tid & 63;
    const int quad = lane >> 4;
    const int l16  = lane & 15;
    const int sw   = l16 & 7;         // pbuf XOR swizzle key

    const int bh = blockIdx.x & 15;   // head -> XCD pinning
    const int qb = (blockIdx.x >> 4) & 7;
    const int ks = blockIdx.x >> 7;   // key-split 0..3
    const int q0 = qb * QTILE + wave * 64;
    const int kbase = ks * KRANGE;

    const unsigned short* __restrict__ Qp = qh + (size_t)bh * SEQ * DH;
    const unsigned short* __restrict__ Kp = kh + (size_t)bh * SEQ * DH;
    const unsigned short* __restrict__ Vp = vt + (size_t)bh * DH * SEQ;

    const int sl    = lane ^ (lane >> 3);
    const int sl16  = sl >> 2, squad = sl & 3;

    // staging role: waves 0-3 stage K quarter kw; waves 4-7 stage V quarter kw
    const int kw = wave & 3;
    const unsigned short* src;
    size_t sstride;
    if (wave < 4) {
        src = Kp + (size_t)(kbase + kw * 16 + sl16) * DH + squad * 8;
        sstride = (size_t)64 * DH;
    } else {
        const int vdh = kw >> 1, vkh = kw & 1;
        src = Vp + (size_t)(vdh * 16 + sl16) * SEQ + kbase + vkh * 32 + squad * 8;
        sstride = 64;
    }
    unsigned short* dstA = (wave < 4) ? &kbuf[0][kw][0][0] : &vbuf[0][kw][0][0];
    unsigned short* dstB = (wave < 4) ? &kbuf[1][kw][0][0] : &vbuf[1][kw][0][0];

    const int s_ = (l16 << 2) | quad;
    const int jj = (s_ & 56) | ((s_ ^ (s_ >> 3)) & 7);

    bf16x8 qf[4];
    #pragma unroll
    for (int i = 0; i < 4; i++)
        qf[i] = *(const bf16x8*)(Qp + (size_t)(q0 + i * 16 + l16) * DH + quad * 8);

    const bf16x8 ones = {0x3F80, 0x3F80, 0x3F80, 0x3F80,
                         0x3F80, 0x3F80, 0x3F80, 0x3F80};

    f32x4 o[4][2];
    f32x4 lones[4];
    #pragma unroll
    for (int i = 0; i < 4; i++) {
        o[i][0] = (f32x4){0.f, 0.f, 0.f, 0.f};
        o[i][1] = (f32x4){0.f, 0.f, 0.f, 0.f};
        lones[i] = (f32x4){0.f, 0.f, 0.f, 0.f};
    }
    const f32x4 z = {0.f, 0.f, 0.f, 0.f};

    // prologue: stage tile 0 into buffer 0 (1 stage16 per wave)
    stage16(src, dstA, lane);
    src += sstride;

    for (int t = 0; t < TILES; t++) {
        const int buf = t & 1;

        __syncthreads();   // tile t staged; buf^1 free

        if (t + 1 < TILES) {
            stage16(src, buf ? dstA : dstB, lane);   // stage into buf^1
            src += sstride;
        }

        // read shared K/V fragments ONCE per wave, reuse across 4 q-subtiles
        bf16x8 kf[4], vf[4];
        #pragma unroll
        for (int c = 0; c < 4; c++) kf[c] = *(const bf16x8*)&kbuf[buf][c][jj][0];
        #pragma unroll
        for (int f = 0; f < 4; f++) vf[f] = *(const bf16x8*)&vbuf[buf][f][jj][0];

        #pragma unroll
        for (int qt = 0; qt < 4; qt++) {
            const int pr = qt & 1;    // pbuf parity region
            #pragma unroll
            for (int c = 0; c < 4; c++) {
                f32x4 s = __builtin_amdgcn_mfma_f32_16x16x32_bf16(kf[c], qf[qt], z, 0, 0, 0);
                float e0 = EXP2(s[0]);
                float e1 = EXP2(s[1]);
                float e2 = EXP2(s[2]);
                float e3 = EXP2(s[3]);
                int chs = ((c * 2 + (quad >> 1)) ^ sw) * 8 + (quad & 1) * 4;
                *(uint2*)&pbuf[wave][pr][l16][chs] =
                    make_uint2(pack_bf2_t(e0, e1), pack_bf2_t(e2, e3));
            }
            bf16x8 pf0 = *(const bf16x8*)&pbuf[wave][pr][l16][((0 + quad) ^ sw) * 8];
            bf16x8 pf1 = *(const bf16x8*)&pbuf[wave][pr][l16][((4 + quad) ^ sw) * 8];
            __builtin_amdgcn_s_setprio(1);   // T5: keep matrix pipe fed in PV
            o[qt][0] = __builtin_amdgcn_mfma_f32_16x16x32_bf16(pf0, vf[0], o[qt][0], 0, 0, 0);
            o[qt][0] = __builtin_amdgcn_mfma_f32_16x16x32_bf16(pf1, vf[1], o[qt][0], 0, 0, 0);
            o[qt][1] = __builtin_amdgcn_mfma_f32_16x16x32_bf16(pf0, vf[2], o[qt][1], 0, 0, 0);
            o[qt][1] = __builtin_amdgcn_mfma_f32_16x16x32_bf16(pf1, vf[3], o[qt][1], 0, 0, 0);
            lones[qt] = __builtin_amdgcn_mfma_f32_16x16x32_bf16(pf0, ones, lones[qt], 0, 0, 0);
            lones[qt] = __builtin_amdgcn_mfma_f32_16x16x32_bf16(pf1, ones, lones[qt], 0, 0, 0);
            __builtin_amdgcn_s_setprio(0);
        }
    }

    // epilogue: bf16 partial O + fp32 partial l (lones rows align with o rows)
    const size_t obase = (size_t)(ks * BH + bh) * SEQ;
    #pragma unroll
    for (int qt = 0; qt < 4; qt++) {
        if (l16 == 0) {
            #pragma unroll
            for (int r = 0; r < 4; r++)
                pl[obase + q0 + qt * 16 + quad * 4 + r] = lones[qt][r];
        }
        #pragma unroll
        for (int r = 0; r < 4; r++) {
            int n = q0 + qt * 16 + quad * 4 + r;
            unsigned short* dst = po + (obase + n) * DH;
            dst[l16]      = f2bf(o[qt][0][r]);
            dst[16 + l16] = f2bf(o[qt][1][r]);
        }
    }
}

// ---------------- merge v2 (R10-proven): uint4 po reads, 32B/thread out -----
__global__ __launch_bounds__(256) void merge_kernel(
    const unsigned short* __restrict__ po, const float* __restrict__ pl,
    float* __restrict__ out)
{
    int t    = blockIdx.x * 256 + threadIdx.x;   // 0 .. 256K-1
    int d16  = t & 3;                            // 16B chunk within 32-dh row
    int pair = t >> 2;
    int bh   = pair >> 12;
    int n    = pair & 4095;
    float s0 = 0.f, s1 = 0.f, s2 = 0.f, s3 = 0.f;
    float s4 = 0.f, s5 = 0.f, s6 = 0.f, s7 = 0.f, ls = 0.f;
    #pragma unroll
    for (int sp = 0; sp < NSPLIT; sp++) {
        size_t base = (size_t)(sp * BH + bh) * SEQ + n;
        uint4 v = ((const uint4*)(po + base * DH))[d16];
        s0 += __builtin_bit_cast(float, v.x << 16);
        s1 += __builtin_bit_cast(float, v.x & 0xFFFF0000u);
        s2 += __builtin_bit_cast(float, v.y << 16);
        s3 += __builtin_bit_cast(float, v.y & 0xFFFF0000u);
        s4 += __builtin_bit_cast(float, v.z << 16);
        s5 += __builtin_bit_cast(float, v.z & 0xFFFF0000u);
        s6 += __builtin_bit_cast(float, v.w << 16);
        s7 += __builtin_bit_cast(float, v.w & 0xFFFF0000u);
        ls += pl[base];
    }
    float inv = 1.f / ls;
    int b = bh >> 3, h = bh & 7;
    float4 o0 = {s0 * inv, s1 * inv, s2 * inv, s3 * inv};
    float4 o1 = {s4 * inv, s5 * inv, s6 * inv, s7 * inv};
    float4* dst = (float4*)(out + ((size_t)b * SEQ + n) * (NH * DH) + h * DH);
    dst[d16 * 2]     = o0;
    dst[d16 * 2 + 1] = o1;
}

extern "C" void kernel_launch(void* const* d_in, const int* in_sizes, int n_in,
                              void* d_out, int out_size, void* d_ws, size_t ws_size,
                              hipStream_t stream)
{
    const float* x  = (const float*)d_in[0];
    const float* Wq = (const float*)d_in[1];
    const float* Wk = (const float*)d_in[2];
    const float* Wv = (const float*)d_in[3];
    float* out = (float*)d_out;

    // ws: qh|kh|vt (4 MiB each) | Wt (384 KiB) | po (16 MiB) | pl (1 MiB) | xb (4 MiB)
    unsigned short* qh = (unsigned short*)d_ws;
    unsigned short* kh = qh + (size_t)BH * SEQ * DH;
    unsigned short* vt = kh + (size_t)BH * SEQ * DH;
    unsigned short* Wt = vt + (size_t)BH * SEQ * DH;
    unsigned short* po = Wt + 3 * DIN * DIN;
    float* pl = (float*)(po + (size_t)NSPLIT * BH * SEQ * DH);
    unsigned short* xb = (unsigned short*)(pl + (size_t)NSPLIT * BH * SEQ);

    prep_kernel<<<dim3(48 + 1024), 256, 0, stream>>>(x, Wq, Wk, Wv, Wt, xb);
    proj_kernel<<<dim3(512, 3), 256, 0, stream>>>(xb, Wt, qh, kh, vt);
    attn_kernel<<<dim3(BH * (SEQ / QTILE) * NSPLIT), 512, 0, stream>>>(qh, kh, vt, po, pl);
    merge_kernel<<<dim3(1024), 256, 0, stream>>>(po, pl, out);
}